// Round 4
// baseline (500.950 us; speedup 1.0000x reference)
//
#include <hip/hip_runtime.h>
#include <math.h>

// Inputs fp32, output buffer fp32. Internal compute fp32.

__device__ __forceinline__ float sigf(float x) { return 1.0f / (1.0f + expf(-x)); }

__device__ __forceinline__ float wave_red(float v) {
#pragma unroll
    for (int s = 32; s; s >>= 1) v += __shfl_down(v, s, 64);
    return v;
}

// dot of 1024 fp32 weights with 1024 fp32 x, one 64-lane wave
__device__ __forceinline__ float dotf(const float* __restrict__ w,
                                      const float* __restrict__ x, int lane) {
    float acc = 0.f;
#pragma unroll
    for (int j = 0; j < 4; ++j) {
        float4 a = *reinterpret_cast<const float4*>(w + j * 256 + lane * 4);
        float4 b = *reinterpret_cast<const float4*>(x + j * 256 + lane * 4);
        acc += a.x * b.x + a.y * b.y + a.z * b.z + a.w * b.w;
    }
    return acc;
}

// ---------------- column max over tsn [4096,1024] ----------------
// 256 blocks x 16 rows each; 4x unrolled for memory-level parallelism.
__global__ void colmax_part_k(const float* __restrict__ tsn, float* __restrict__ part) {
    int tid = threadIdx.x;
    const float4* t4 = reinterpret_cast<const float4*>(tsn);
    float4 m = make_float4(-INFINITY, -INFINITY, -INFINITY, -INFINITY);
    int r0 = blockIdx.x * 16;
    for (int r = r0; r < r0 + 16; r += 4) {
        float4 v0 = t4[(size_t)(r + 0) * 256 + tid];
        float4 v1 = t4[(size_t)(r + 1) * 256 + tid];
        float4 v2 = t4[(size_t)(r + 2) * 256 + tid];
        float4 v3 = t4[(size_t)(r + 3) * 256 + tid];
        m.x = fmaxf(fmaxf(m.x, v0.x), fmaxf(v1.x, fmaxf(v2.x, v3.x)));
        m.y = fmaxf(fmaxf(m.y, v0.y), fmaxf(v1.y, fmaxf(v2.y, v3.y)));
        m.z = fmaxf(fmaxf(m.z, v0.z), fmaxf(v1.z, fmaxf(v2.z, v3.z)));
        m.w = fmaxf(fmaxf(m.w, v0.w), fmaxf(v1.w, fmaxf(v2.w, v3.w)));
    }
    reinterpret_cast<float4*>(part + (size_t)blockIdx.x * 1024)[tid] = m;
}
__global__ void colmax_fin_k(const float* __restrict__ part, float* __restrict__ maxv) {
    int c = blockIdx.x * 256 + threadIdx.x;
    float m = -INFINITY;
    for (int b = 0; b < 256; ++b) m = fmaxf(m, part[b * 1024 + c]);
    maxv[c] = m;
}

// ---------------- generic GEMV (small, W_fe only) ----------------
__global__ void gemv_k(const float* __restrict__ W, int ld, int nrows,
                       const float* __restrict__ xA,
                       const float* __restrict__ b1,
                       float* __restrict__ yF) {
    int wave = threadIdx.x >> 6, lane = threadIdx.x & 63;
    int row = blockIdx.x * 4 + wave;
    if (row >= nrows) return;
    float acc = dotf(W + (size_t)row * ld, xA, lane);
    acc = wave_red(acc);
    if (lane == 0) yF[row] = acc + b1[row];
}

// ---------------- unified LSTM step: gates GEMV + cell ----------------
// Grid: 1024 blocks (one per hidden unit j), 512 threads = 8 waves.
// Wave w: gate = w>>1, half = w&1; row = gate*1024 + j.
// Partial dot over cols [off + half*halflen, off + (half+1)*halflen), halflen = nr*256.
// gates[row] = dot + b1[row] + b2[row] + gxIn[row]; optionally written to gxOut.
// cell (thread 0): c = sig(i)*tanh(g) [+ sig(f)*cc_in[j]]; h = sig(o)*tanh(c).
__global__ __launch_bounds__(512) void lstm_step_k(
    const float* __restrict__ W, int ld, int off, int nr,
    const float* __restrict__ x,
    const float* __restrict__ b1, const float* __restrict__ b2,
    const float* __restrict__ gxIn, float* __restrict__ gxOut,
    const float* __restrict__ cc_in, float* __restrict__ cc_out,
    float* __restrict__ h_out) {
    __shared__ float part[8];
    int tid = threadIdx.x;
    int w = tid >> 6, lane = tid & 63;
    int gate = w >> 1, half = w & 1;
    int j = blockIdx.x;
    int row = gate * 1024 + j;
    int halflen = nr * 256;
    const float* wr = W + (size_t)row * ld + off + half * halflen;
    const float* xr = x + half * halflen;
    float acc = 0.f;
    for (int r = 0; r < nr; ++r) {
        float4 a = *reinterpret_cast<const float4*>(wr + r * 256 + lane * 4);
        float4 b = *reinterpret_cast<const float4*>(xr + r * 256 + lane * 4);
        acc += a.x * b.x + a.y * b.y + a.z * b.z + a.w * b.w;
    }
    acc = wave_red(acc);
    if (lane == 0) part[w] = acc;
    __syncthreads();
    if (tid == 0) {
        float g4[4];
#pragma unroll
        for (int gi = 0; gi < 4; ++gi) {
            int rw = gi * 1024 + j;
            float v = part[2 * gi] + part[2 * gi + 1];
            if (b1) v += b1[rw];
            if (b2) v += b2[rw];
            if (gxIn) v += gxIn[rw];
            if (gxOut) gxOut[rw] = v;
            g4[gi] = v;
        }
        float c = sigf(g4[0]) * tanhf(g4[2]);
        if (cc_in) c += sigf(g4[1]) * cc_in[j];
        float h = sigf(g4[3]) * tanhf(c);
        if (cc_out) cc_out[j] = c;
        h_out[j] = h;
    }
}

// ---------------- fused sv + nfs ----------------
// nfs[t][i] = relu( dot(Wp[i,0:1024], f_in) + dot(Wp[i,2048:3072], g) + bp[i]
//                   + dot(Wp[i,1024:2048], ajs[t]) ),  t = 0..9
__global__ void nfs_sv_k(const float* __restrict__ Wp, const float* __restrict__ f_in,
                         const float* __restrict__ g, const float* __restrict__ bp,
                         const float* __restrict__ ajs, float* __restrict__ nfs) {
    int wave = threadIdx.x >> 6, lane = threadIdx.x & 63;
    int i = blockIdx.x * 4 + wave;
    const float* wr = Wp + (size_t)i * 3072;
    float svacc = dotf(wr, f_in, lane) + dotf(wr + 2048, g, lane);
    float wf[16];
#pragma unroll
    for (int j = 0; j < 4; ++j) {
        float4 a = *reinterpret_cast<const float4*>(wr + 1024 + j * 256 + lane * 4);
        wf[j * 4 + 0] = a.x; wf[j * 4 + 1] = a.y; wf[j * 4 + 2] = a.z; wf[j * 4 + 3] = a.w;
    }
    float acc[10];
#pragma unroll
    for (int t = 0; t < 10; ++t) acc[t] = 0.f;
#pragma unroll
    for (int t = 0; t < 10; ++t) {
        const float* a = ajs + t * 1024;
#pragma unroll
        for (int j = 0; j < 4; ++j) {
            float4 b = *reinterpret_cast<const float4*>(a + j * 256 + lane * 4);
            acc[t] += wf[j * 4 + 0] * b.x + wf[j * 4 + 1] * b.y +
                      wf[j * 4 + 2] * b.z + wf[j * 4 + 3] * b.w;
        }
    }
    float svr = wave_red(svacc);
#pragma unroll
    for (int t = 0; t < 10; ++t) {
        float r = wave_red(acc[t]);
        if (lane == 0) nfs[t * 1024 + i] = fmaxf(svr + bp[i] + r, 0.f);
    }
}

// scores of expansion 1 + bd0 + argmin + extraction of a2in/f2in (also writes f2in output)
__global__ void scores1_k(const float* __restrict__ nfs1, const float* __restrict__ g,
                          const float* __restrict__ fs, const float* __restrict__ ajs1,
                          float* __restrict__ s1, float* __restrict__ bd1_out,
                          int* __restrict__ istar_out, float* __restrict__ a2in,
                          float* __restrict__ f2in, float* __restrict__ out_f2in) {
    __shared__ float red[256];
    __shared__ float d[11];
    __shared__ int istar_sh;
    int tid = threadIdx.x;
    for (int t = 0; t < 11; ++t) {
        const float* v = (t < 10) ? (nfs1 + t * 1024) : fs;
        float p = 0.f;
        for (int j = tid * 4; j < tid * 4 + 4; ++j) { float df = v[j] - g[j]; p += df * df; }
        red[tid] = p; __syncthreads();
        for (int s = 128; s; s >>= 1) { if (tid < s) red[tid] += red[tid + s]; __syncthreads(); }
        if (tid == 0) d[t] = red[0] * (1.0f / 1024.0f);
        __syncthreads();
    }
    if (tid == 0) {
        float bd = d[10];  // bd0
        float smin = INFINITY; int im = 0;
        for (int t = 0; t < 10; ++t) {
            float s = bd - d[t];
            s1[t] = s;
            if (s < smin) { smin = s; im = t; }
            if (d[t] < bd) bd = d[t];
        }
        *bd1_out = bd; *istar_out = im; istar_sh = im;
    }
    __syncthreads();
    int im = istar_sh;
    for (int j = tid; j < 1024; j += 256) {
        float a = ajs1[im * 1024 + j], f = nfs1[im * 1024 + j];
        a2in[j] = a; f2in[j] = f; out_f2in[j] = f;
    }
}

// scores of expansion 2 + top-2 select + pa/pfeat/pgoal outputs
__global__ void scores2_k(const float* __restrict__ nfs2, const float* __restrict__ g,
                          const float* __restrict__ fs, const float* __restrict__ ajs1,
                          const float* __restrict__ nfs1, const float* __restrict__ ajs2,
                          const float* __restrict__ a2in, const float* __restrict__ f2in,
                          const float* __restrict__ s1, const float* __restrict__ bd1,
                          const int* __restrict__ istar, float* __restrict__ pa,
                          float* __restrict__ out) {
    __shared__ float red[256];
    __shared__ float d[10];
    __shared__ int sel[2];
    int tid = threadIdx.x;
    for (int t = 0; t < 10; ++t) {
        const float* v = nfs2 + t * 1024;
        float p = 0.f;
        for (int j = tid * 4; j < tid * 4 + 4; ++j) { float df = v[j] - g[j]; p += df * df; }
        red[tid] = p; __syncthreads();
        for (int s = 128; s; s >>= 1) { if (tid < s) red[tid] += red[tid + s]; __syncthreads(); }
        if (tid == 0) d[t] = red[0] * (1.0f / 1024.0f);
        __syncthreads();
    }
    if (tid == 0) {
        float sc[20];
        int im = *istar;
        for (int t = 0; t < 10; ++t) sc[t] = (t == im) ? INFINITY : s1[t];
        float bd = *bd1;
        for (int t = 0; t < 10; ++t) {
            float s = bd - d[t];
            sc[10 + t] = s;
            if (d[t] < bd) bd = d[t];
        }
        int i0 = 0; float m0 = INFINITY;
        for (int t = 0; t < 20; ++t) if (sc[t] < m0) { m0 = sc[t]; i0 = t; }
        int i1 = 0; float m1 = INFINITY;
        for (int t = 0; t < 20; ++t) { if (t == i0) continue; if (sc[t] < m1) { m1 = sc[t]; i1 = t; } }
        sel[0] = i0; sel[1] = i1;
    }
    __syncthreads();
    for (int p = 0; p < 2; ++p) {
        int idx = sel[p];
        for (int j = tid; j < 1024; j += 256) {
            float av, fv;
            if (idx < 10) {
                av = ajs1[idx * 1024 + j] * 0.5f;
                fv = (fs[j] + nfs1[idx * 1024 + j]) * 0.5f;
            } else {
                int t = idx - 10;
                av = (a2in[j] + ajs2[t * 1024 + j]) * (1.0f / 3.0f);
                fv = (fs[j] + f2in[j] + nfs2[t * 1024 + j]) * (1.0f / 3.0f);
            }
            pa[p * 1024 + j] = av;
            out[5980 + p * 1024 + j] = fv;   // pfeat
            out[8028 + p * 1024 + j] = g[j]; // pgoal
        }
    }
}

// heads: pred_actions/verbs/nouns for the 2 selected rows, plus cur_action (We2a @ fs)
__global__ void heads_k(const float* __restrict__ We2a, const float* __restrict__ be2a,
                        const float* __restrict__ We2v, const float* __restrict__ be2v,
                        const float* __restrict__ We2n, const float* __restrict__ be2n,
                        const float* __restrict__ fs, const float* __restrict__ pa,
                        float* __restrict__ out) {
    int wave = threadIdx.x >> 6, lane = threadIdx.x & 63;
    int task = blockIdx.x * 4 + wave;
    if (task >= 2990) return;
    const float* W; const float* b; int rr, o0, o1, o2; bool doFs;
    if (task < 2513)      { W = We2a; b = be2a; rr = task;        o0 = rr;        o1 = 2513 + rr; o2 = 11100 + rr; doFs = true; }
    else if (task < 2638) { W = We2v; b = be2v; rr = task - 2513; o0 = 5026 + rr; o1 = 5151 + rr; o2 = 0; doFs = false; }
    else                  { W = We2n; b = be2n; rr = task - 2638; o0 = 5276 + rr; o1 = 5628 + rr; o2 = 0; doFs = false; }
    const float* wr = W + (size_t)rr * 1024;
    float a0 = 0.f, a1 = 0.f, a2 = 0.f;
#pragma unroll
    for (int r = 0; r < 4; ++r) {
        int base = r * 256 + lane * 4;
        float4 wv = *reinterpret_cast<const float4*>(wr + base);
        float4 p0 = *reinterpret_cast<const float4*>(pa + base);
        float4 p1 = *reinterpret_cast<const float4*>(pa + 1024 + base);
        float4 fv = *reinterpret_cast<const float4*>(fs + base);
        a0 += wv.x * p0.x + wv.y * p0.y + wv.z * p0.z + wv.w * p0.w;
        a1 += wv.x * p1.x + wv.y * p1.y + wv.z * p1.z + wv.w * p1.w;
        a2 += wv.x * fv.x + wv.y * fv.y + wv.z * fv.z + wv.w * fv.w;
    }
    a0 = wave_red(a0); a1 = wave_red(a1); a2 = wave_red(a2);
    if (lane == 0) {
        float bb = b[rr];
        out[o0] = a0 + bb;
        out[o1] = a1 + bb;
        if (doFs) out[o2] = a2 + bb;
    }
}

extern "C" void kernel_launch(void* const* d_in, const int* in_sizes, int n_in,
                              void* d_out, int out_size, void* d_ws, size_t ws_size,
                              hipStream_t stream) {
    const float* tsn    = (const float*)d_in[0];
    const float* W_fe   = (const float*)d_in[1];
    const float* b_fe   = (const float*)d_in[2];
    const float* gW_ih0 = (const float*)d_in[3];
    const float* gW_ihR = (const float*)d_in[4];
    // d_in[5] = gW_hh: multiplied by zero hidden state -> never needed
    const float* gb_ih  = (const float*)d_in[6];
    const float* gb_hh  = (const float*)d_in[7];
    const float* rW_ih  = (const float*)d_in[8];
    const float* rW_hh  = (const float*)d_in[9];
    const float* rb_ih  = (const float*)d_in[10];
    const float* rb_hh  = (const float*)d_in[11];
    const float* Wp     = (const float*)d_in[12];
    const float* bp     = (const float*)d_in[13];
    const float* We2a   = (const float*)d_in[14];
    const float* be2a   = (const float*)d_in[15];
    const float* We2v   = (const float*)d_in[16];
    const float* be2v   = (const float*)d_in[17];
    const float* We2n   = (const float*)d_in[18];
    const float* be2n   = (const float*)d_in[19];
    float* out = (float*)d_out;

    float* w = (float*)d_ws;
    float* part  = w + 0;         // 256*1024
    float* maxv  = w + 262144;    // 1024
    float* fs    = w + 263168;    // 1024
    float* hgA   = w + 264192;    // 1024 (final goal g lives here)
    float* hgB   = w + 265216;    // 1024
    float* gx    = w + 266240;    // 4096
    float* ajs1  = w + 270336;    // 10*1024
    float* nfs1  = w + 280576;    // 10*1024
    float* ajs2  = w + 290816;    // 10*1024
    float* nfs2  = w + 301056;    // 10*1024
    float* cc0   = w + 311296;    // 1024
    float* cc1   = w + 312320;    // 1024
    float* xin2  = w + 313344;    // 2048: a2in | f2in contiguous
    float* a2in  = xin2;
    float* f2in  = xin2 + 1024;
    float* pa    = w + 315392;    // 2*1024
    float* s1    = w + 317440;    // 10
    float* bd1   = w + 317456;    // 1
    int*   istar = (int*)(w + 317460);

    // 1) fs = max(tsn, axis=0) @ W_fe.T + b_fe
    colmax_part_k<<<256, 256, 0, stream>>>(tsn, part);
    colmax_fin_k<<<4, 256, 0, stream>>>(part, maxv);
    gemv_k<<<256, 256, 0, stream>>>(W_fe, 1024, 1024, maxv, b_fe, fs);

    // 2) goal LSTM: 5 layers, zero states => gates = x @ Wih.T + (gb_ih+gb_hh)
    lstm_step_k<<<1024, 512, 0, stream>>>(gW_ih0, 2048, 0, 2, fs, gb_ih, gb_hh,
                                          nullptr, nullptr, nullptr, nullptr, hgA);
    lstm_step_k<<<1024, 512, 0, stream>>>(gW_ihR + (size_t)0 * 4194304, 1024, 0, 2, hgA,
                                          gb_ih + 4096, gb_hh + 4096, nullptr, nullptr, nullptr, nullptr, hgB);
    lstm_step_k<<<1024, 512, 0, stream>>>(gW_ihR + (size_t)1 * 4194304, 1024, 0, 2, hgB,
                                          gb_ih + 8192, gb_hh + 8192, nullptr, nullptr, nullptr, nullptr, hgA);
    lstm_step_k<<<1024, 512, 0, stream>>>(gW_ihR + (size_t)2 * 4194304, 1024, 0, 2, hgA,
                                          gb_ih + 12288, gb_hh + 12288, nullptr, nullptr, nullptr, nullptr, hgB);
    lstm_step_k<<<1024, 512, 0, stream>>>(gW_ihR + (size_t)3 * 4194304, 1024, 0, 2, hgB,
                                          gb_ih + 16384, gb_hh + 16384, nullptr, nullptr, nullptr, nullptr, hgA);
    float* g = hgA;

    // 3) expansion 1: xin = concat(0, fs) -> cols 1024:2048 of rW_ih; writes gx for steps 1-9
    lstm_step_k<<<1024, 512, 0, stream>>>(rW_ih, 2048, 1024, 2, fs, rb_ih, rb_hh,
                                          nullptr, gx, nullptr, cc0, ajs1);
    for (int t = 1; t < 10; ++t) {
        float* cin = ((t - 1) & 1) ? cc1 : cc0;
        float* cout = (t & 1) ? cc1 : cc0;
        lstm_step_k<<<1024, 512, 0, stream>>>(rW_hh, 1024, 0, 2, ajs1 + (t - 1) * 1024,
                                              nullptr, nullptr, gx, nullptr, cin, cout, ajs1 + t * 1024);
    }
    nfs_sv_k<<<256, 256, 0, stream>>>(Wp, fs, g, bp, ajs1, nfs1);
    scores1_k<<<1, 256, 0, stream>>>(nfs1, g, fs, ajs1, s1, bd1, istar, a2in, f2in, out + 10076);

    // 4) expansion 2: xin = concat(a2in, f2in) contiguous -> full 2048-dot
    lstm_step_k<<<1024, 512, 0, stream>>>(rW_ih, 2048, 0, 4, xin2, rb_ih, rb_hh,
                                          nullptr, gx, nullptr, cc0, ajs2);
    for (int t = 1; t < 10; ++t) {
        float* cin = ((t - 1) & 1) ? cc1 : cc0;
        float* cout = (t & 1) ? cc1 : cc0;
        lstm_step_k<<<1024, 512, 0, stream>>>(rW_hh, 1024, 0, 2, ajs2 + (t - 1) * 1024,
                                              nullptr, nullptr, gx, nullptr, cin, cout, ajs2 + t * 1024);
    }
    nfs_sv_k<<<256, 256, 0, stream>>>(Wp, f2in, g, bp, ajs2, nfs2);
    scores2_k<<<1, 256, 0, stream>>>(nfs2, g, fs, ajs1, nfs1, ajs2, a2in, f2in, s1, bd1, istar, pa, out);

    // 5) heads (+ cur_action fused: each We2a row dotted with fs too)
    heads_k<<<748, 256, 0, stream>>>(We2a, be2a, We2v, be2v, We2n, be2n, fs, pa, out);
}